// Round 2
// baseline (233.670 us; speedup 1.0000x reference)
//
#include <hip/hip_runtime.h>
#include <hip/hip_bf16.h>

// GroupLinear: out[t] = x[t] @ w[gid(t)].T
// T=8192, G=8, K=1024, N=2048; groups = contiguous token ranges (cum end-offs).
//
// R7 = R5's verified 128x128 GEMM structure + W-conversion fused into staging:
//  - A (x): bf16 via global_load_lds from workspace (R5 path, byte-identical:
//    pre-swizzled global source, linear LDS dest).
//  - B (w): read fp32 DIRECTLY from the input, reg-stage -> cvt -> swizzled
//    ds_write_b128. Same LDS swizzle invariant as R5, so fragment reads and
//    epilogue are unchanged. Removes the W leg of the cvt pass entirely
//    (was: 64MB fp32 read + 32MB bf16 write + 32MB bf16 GEMM re-read).
//  - cvt kernel now converts X only (48MB traffic, ~10us).
//  - Counted-vmcnt 2-barrier loop (T14 lite, m249 +3%): issue A gload_lds,
//    vmcnt(4)=B(kk) regs ready, ds_write B, issue B(kk+1), vmcnt(8)=A in LDS
//    with B(kk+1) still in flight, barrier, compute, barrier. Issue order
//    A-before-B pinned by asm memory fences (vmcnt is a FIFO count).
//  - n-major XCD swizzle: each XCD owns 2 n-blocks x all 72 pairs -> per-expert
//    W fp32 residency = 1MB < 4MB L2 (R6's pair-major chunking would need 8MB).
//  - Occupancy preserved: 32KB LDS, arch VGPR ~100, launch_bounds(256,4)
//    -> 4 blocks/CU, 16 waves/CU (the TLP that carries the 2-barrier loop).

#define T_DIM 8192
#define G_DIM 8
#define K_DIM 1024
#define N_DIM 2048
#define MAX_PAIRS 72   // 64 m-tiles + <=7 boundary duplicates, rounded up (%8==0)
#define NT (K_DIM / 64)

using short8  = __attribute__((ext_vector_type(8))) short;   // 8 bf16
using f32x4   = __attribute__((ext_vector_type(4))) float;
using ushort8 = __attribute__((ext_vector_type(8))) unsigned short;

typedef __attribute__((address_space(1))) void gvoid;  // global
typedef __attribute__((address_space(3))) void lvoid;  // LDS

// ---------------- fp32 -> bf16 convert, X ONLY (grid-stride, nt loads) ------
__global__ __launch_bounds__(256) void cvt_x_kernel(const float* __restrict__ x,
                                                    ushort8* __restrict__ xb,
                                                    int n8) {
  const int stride = gridDim.x * blockDim.x;
  for (int i = blockIdx.x * blockDim.x + threadIdx.x; i < n8; i += stride) {
    f32x4 v0 = __builtin_nontemporal_load(&((const f32x4*)x)[2 * i]);
    f32x4 v1 = __builtin_nontemporal_load(&((const f32x4*)x)[2 * i + 1]);
    ushort8 o;
    o[0] = __builtin_bit_cast(unsigned short, __float2bfloat16(v0[0]));
    o[1] = __builtin_bit_cast(unsigned short, __float2bfloat16(v0[1]));
    o[2] = __builtin_bit_cast(unsigned short, __float2bfloat16(v0[2]));
    o[3] = __builtin_bit_cast(unsigned short, __float2bfloat16(v0[3]));
    o[4] = __builtin_bit_cast(unsigned short, __float2bfloat16(v1[0]));
    o[5] = __builtin_bit_cast(unsigned short, __float2bfloat16(v1[1]));
    o[6] = __builtin_bit_cast(unsigned short, __float2bfloat16(v1[2]));
    o[7] = __builtin_bit_cast(unsigned short, __float2bfloat16(v1[3]));
    xb[i] = o;
  }
}

// ---------------- grouped GEMM: A=bf16 gload_lds, B=fp32 reg-stage+cvt ------
__global__ __launch_bounds__(256, 4) void grouped_gemm_kernel(
    const __hip_bfloat16* __restrict__ xb,
    const float* __restrict__ w,
    const int* __restrict__ offs,
    float* __restrict__ out) {
  // ---- n-major XCD swizzle: HW assigns block v to XCD v%8; XCD c owns
  // n-blocks {2c, 2c+1} sweeping all pairs -> W slice read once, 1MB/expert L2.
  const int v  = blockIdx.y * 16 + blockIdx.x;   // grid (16,72), 1152 blocks
  const int c  = v & 7;
  const int l  = v >> 3;                          // 0..143
  const int nb = c * 2 + (l & 1);                 // 0..15
  const int p  = l >> 1;                          // 0..71
  const int n0 = nb * 128;

  // ---- map pair p -> (expert g, m-tile) via prefix sum of 128-row tile spans
  int offv[G_DIM];
#pragma unroll
  for (int i = 0; i < G_DIM; ++i) offv[i] = offs[i];

  int g = -1, tile = 0, lo = 0, hi = 0, pre = 0;
#pragma unroll
  for (int gi = 0; gi < G_DIM; ++gi) {
    const int lb = gi ? offv[gi - 1] : 0;
    const int hb = offv[gi];
    const int t0 = lb >> 7;
    const int cnt = (hb > lb) ? (((hb + 127) >> 7) - t0) : 0;
    if (g < 0 && p < pre + cnt) { g = gi; tile = t0 + (p - pre); lo = lb; hi = hb; }
    pre += cnt;
  }
  if (g < 0) return;  // dead pair; uniform per block, before any barrier

  const int m0 = tile * 128;

  __shared__ __align__(16) __hip_bfloat16 As[128 * 64];  // 16 KB
  __shared__ __align__(16) __hip_bfloat16 Bs[128 * 64];  // 16 KB

  const int lane = threadIdx.x & 63;
  const int wid  = threadIdx.x >> 6;
  const int wm   = wid >> 1;
  const int wn   = wid & 1;

  // staging: chunk j = 8 rows x 64 cols; lane -> (srow=lane>>3, col-slot lane&7)
  const int srow = lane >> 3;
  const int scol = ((lane & 7) ^ srow) * 8;  // swizzled col-slot (elems)
  const int lcol = (lane & 7) * 8;           // linear col-slot (elems)

  // A: pre-swizzled global source, linear LDS dest (gload_lds lane*16B rule).
  // B: linear fp32 global source, swizzled LDS write (we control the address).
  const __hip_bfloat16* gA[4];
  const float*          gB[4];
  __hip_bfloat16*       Bd[4];
#pragma unroll
  for (int i = 0; i < 4; ++i) {
    const int j   = wid * 4 + i;            // chunk 0..15
    const int row = j * 8 + srow;
    gA[i] = xb + (size_t)(m0 + row) * K_DIM + scol;
    gB[i] = w + ((size_t)g * N_DIM + n0 + row) * K_DIM + lcol;
    Bd[i] = Bs + j * 512 + srow * 64 + scol;
  }

  f32x4 breg[4][2];

  f32x4 acc[4][4] = {};

  // ---- prologue: issue B(0)
#pragma unroll
  for (int i = 0; i < 4; ++i) {
    breg[i][0] = *(const f32x4*)(gB[i]);
    breg[i][1] = *(const f32x4*)(gB[i] + 4);
  }

  for (int kk = 0; kk < NT; ++kk) {
    const int k0 = kk * 64;
    // issue A(kk): 4 async gload_lds (vmcnt FIFO: these are OLDER than B(kk+1))
#pragma unroll
    for (int i = 0; i < 4; ++i)
      __builtin_amdgcn_global_load_lds((gvoid*)(gA[i] + k0),
                                       (lvoid*)(As + (wid * 4 + i) * 512), 16, 0, 0);
    // B(kk) regs ready when only A(kk)'s 4 loads remain outstanding
    asm volatile("s_waitcnt vmcnt(4)" ::: "memory");
#pragma unroll
    for (int i = 0; i < 4; ++i) {
      ushort8 o;
      o[0] = __builtin_bit_cast(unsigned short, __float2bfloat16(breg[i][0][0]));
      o[1] = __builtin_bit_cast(unsigned short, __float2bfloat16(breg[i][0][1]));
      o[2] = __builtin_bit_cast(unsigned short, __float2bfloat16(breg[i][0][2]));
      o[3] = __builtin_bit_cast(unsigned short, __float2bfloat16(breg[i][0][3]));
      o[4] = __builtin_bit_cast(unsigned short, __float2bfloat16(breg[i][1][0]));
      o[5] = __builtin_bit_cast(unsigned short, __float2bfloat16(breg[i][1][1]));
      o[6] = __builtin_bit_cast(unsigned short, __float2bfloat16(breg[i][1][2]));
      o[7] = __builtin_bit_cast(unsigned short, __float2bfloat16(breg[i][1][3]));
      *(ushort8*)(Bd[i]) = o;  // ds_write_b128, conflict-free (XOR perm per row)
    }
    if (kk + 1 < NT) {
      // early-issue B(kk+1) (T14): newest 8 VMEM ops, allowed to fly across
      // the barrier; consumed next iter at vmcnt(4).
#pragma unroll
      for (int i = 0; i < 4; ++i) {
        breg[i][0] = *(const f32x4*)(gB[i] + k0 + 64);
        breg[i][1] = *(const f32x4*)(gB[i] + k0 + 64 + 4);
      }
      // A(kk) in LDS (allow B(kk+1)'s 8 in flight); own ds_writes drained
      asm volatile("s_waitcnt vmcnt(8) lgkmcnt(0)" ::: "memory");
    } else {
      asm volatile("s_waitcnt vmcnt(0) lgkmcnt(0)" ::: "memory");
    }
    __builtin_amdgcn_s_barrier();
    asm volatile("" ::: "memory");

    // ---- compute tile kk (byte-identical to R5's verified fragment path)
#pragma unroll
    for (int ks = 0; ks < 2; ++ks) {
      const int kb  = ks * 4 + (lane >> 4);
      const int off = ((kb ^ (lane & 7)) * 8);
      short8 a[4], b[4];
#pragma unroll
      for (int mt = 0; mt < 4; ++mt)
        a[mt] = *reinterpret_cast<const short8*>(
            As + (wm * 64 + mt * 16 + (lane & 15)) * 64 + off);
#pragma unroll
      for (int nt = 0; nt < 4; ++nt)
        b[nt] = *reinterpret_cast<const short8*>(
            Bs + (wn * 64 + nt * 16 + (lane & 15)) * 64 + off);
#pragma unroll
      for (int mt = 0; mt < 4; ++mt)
#pragma unroll
        for (int nt = 0; nt < 4; ++nt)
          acc[mt][nt] = __builtin_amdgcn_mfma_f32_16x16x32_bf16(
              a[mt], b[nt], acc[mt][nt], 0, 0, 0);
    }
    asm volatile("" ::: "memory");
    __builtin_amdgcn_s_barrier();
  }

  // ---- epilogue: C/D layout col=lane&15, row=(lane>>4)*4+reg [m89-verified];
  // store only rows in [lo,hi) — boundary tiles written disjointly per expert.
  const int quad = lane >> 4;
#pragma unroll
  for (int mt = 0; mt < 4; ++mt) {
    const int rbase = m0 + wm * 64 + mt * 16 + quad * 4;
#pragma unroll
    for (int r = 0; r < 4; ++r) {
      const int row = rbase + r;
      if (row < lo || row >= hi) continue;
#pragma unroll
      for (int nt = 0; nt < 4; ++nt) {
        const int col = n0 + wn * 64 + nt * 16 + (lane & 15);
        out[(size_t)row * N_DIM + col] = acc[mt][nt][r];
      }
    }
  }
}

// ---------------- fp32 fallback (only if d_ws < 16 MB; correctness-only) ----
__global__ __launch_bounds__(256) void fallback_kernel(
    const float* __restrict__ x, const float* __restrict__ w,
    const int* __restrict__ offs, float* __restrict__ out) {
  __shared__ float xs[K_DIM];
  const int t = blockIdx.y;
  int g = 0;
  while (g < G_DIM - 1 && offs[g] <= t) ++g;
  for (int i = threadIdx.x; i < K_DIM; i += blockDim.x)
    xs[i] = x[(size_t)t * K_DIM + i];
  __syncthreads();
  const int n = blockIdx.x * blockDim.x + threadIdx.x;
  const float* wr = w + ((size_t)g * N_DIM + n) * K_DIM;
  float s = 0.f;
  for (int k = 0; k < K_DIM; ++k) s += xs[k] * wr[k];
  out[(size_t)t * N_DIM + n] = s;
}

extern "C" void kernel_launch(void* const* d_in, const int* in_sizes, int n_in,
                              void* d_out, int out_size, void* d_ws, size_t ws_size,
                              hipStream_t stream) {
  const float* x    = (const float*)d_in[0];
  const float* w    = (const float*)d_in[1];
  const int*   offs = (const int*)d_in[2];
  float*       out  = (float*)d_out;

  const size_t x_elems = (size_t)T_DIM * K_DIM;                    // 8.39M
  const size_t need    = x_elems * sizeof(__hip_bfloat16);         // 16 MiB

  if (ws_size < need) {
    fallback_kernel<<<dim3(N_DIM / 256, T_DIM), 256, 0, stream>>>(x, w, offs, out);
    return;
  }

  __hip_bfloat16* xb = (__hip_bfloat16*)d_ws;
  const int n8 = (int)(x_elems / 8);  // 1,048,576

  cvt_x_kernel<<<2048, 256, 0, stream>>>(x, (ushort8*)xb, n8);

  grouped_gemm_kernel<<<dim3(16, MAX_PAIRS), 256, 0, stream>>>(xb, w, offs, out);
}

// Round 3
// 194.429 us; speedup vs baseline: 1.2018x; 1.2018x over previous
//
#include <hip/hip_runtime.h>
#include <hip/hip_bf16.h>

// GroupLinear: out[t] = x[t] @ w[gid(t)].T
// T=8192, G=8, K=1024, N=2048; groups = contiguous token ranges (cum end-offs).
//
// R8 = R5's verified structure (full cvt pass -> bf16 workspace; gload_lds for
// BOTH operands; plain __syncthreads 2-barrier loop) with geometry/placement:
//  - BN 128 -> 256: 8 waves (2Mx4N), 512 threads, 48KB LDS, launch_bounds(512,4)
//    -> 2 blocks x 8 waves = 16 waves/CU (same TLP as R5's 4x4). Halves the
//    X logical L2-miss stream (8 column-block readers instead of 16):
//    576 -> 432 MB logical. R6 proved this shape's FETCH drop; its regression
//    was the 144KB-LDS occupancy collapse, which this config avoids.
//  - R6's pair-major XCD swizzle (FETCH 84.5 -> 57 MB measured): XCD c owns
//    pairs [9c, 9c+9) x all 8 n-blocks; 72 = 8*9 so mapping is bijective.
//  - R7 lesson (reverted): reading W as fp32 in the GEMM doubles the dominant
//    logical stream (576MB) and thrashes L2 -> 2.3x regression. The separate
//    cvt pass pays 96MB HBM to halve the GEMM's logical traffic. Keep it.
//  - Fragment reads, XOR swizzle invariant (row&7 ^ col-slot), epilogue C/D
//    mapping and boundary row-masking identical to R5.

#define T_DIM 8192
#define G_DIM 8
#define K_DIM 1024
#define N_DIM 2048
#define MAX_PAIRS 72        // 64 m-tiles + <=7 boundary duplicates (%8==0)
#define PPX (MAX_PAIRS / 8) // 9 pairs per XCD
#define NT (K_DIM / 64)

using short8  = __attribute__((ext_vector_type(8))) short;   // 8 bf16
using f32x4   = __attribute__((ext_vector_type(4))) float;
using ushort8 = __attribute__((ext_vector_type(8))) unsigned short;

typedef __attribute__((address_space(1))) void gvoid;  // global
typedef __attribute__((address_space(3))) void lvoid;  // LDS

// ---------------- fp32 -> bf16 convert (grid-stride, 2x unroll, nt loads) ---
__global__ __launch_bounds__(256) void cvt_kernel(const float* __restrict__ x,
                                                  const float* __restrict__ w,
                                                  ushort8* __restrict__ xb,
                                                  ushort8* __restrict__ wb,
                                                  int n8x, int n8tot) {
  const int stride = gridDim.x * blockDim.x;
  for (int i = blockIdx.x * blockDim.x + threadIdx.x; i < n8tot; i += 2 * stride) {
#pragma unroll
    for (int u = 0; u < 2; ++u) {
      const int idx = i + u * stride;
      if (idx >= n8tot) break;
      const f32x4* s; ushort8* d; int j;
      if (idx < n8x) { s = (const f32x4*)x; d = xb; j = idx; }
      else           { s = (const f32x4*)w; d = wb; j = idx - n8x; }
      f32x4 v0 = __builtin_nontemporal_load(&s[2 * j]);
      f32x4 v1 = __builtin_nontemporal_load(&s[2 * j + 1]);
      ushort8 o;
      o[0] = __builtin_bit_cast(unsigned short, __float2bfloat16(v0[0]));
      o[1] = __builtin_bit_cast(unsigned short, __float2bfloat16(v0[1]));
      o[2] = __builtin_bit_cast(unsigned short, __float2bfloat16(v0[2]));
      o[3] = __builtin_bit_cast(unsigned short, __float2bfloat16(v0[3]));
      o[4] = __builtin_bit_cast(unsigned short, __float2bfloat16(v1[0]));
      o[5] = __builtin_bit_cast(unsigned short, __float2bfloat16(v1[1]));
      o[6] = __builtin_bit_cast(unsigned short, __float2bfloat16(v1[2]));
      o[7] = __builtin_bit_cast(unsigned short, __float2bfloat16(v1[3]));
      d[j] = o;
    }
  }
}

// ---------------- grouped bf16 GEMM: 128x256 tile, 8 waves, R5 sync ---------
__global__ __launch_bounds__(512, 4) void grouped_gemm_kernel(
    const __hip_bfloat16* __restrict__ xb,
    const __hip_bfloat16* __restrict__ wb,
    const int* __restrict__ offs,
    float* __restrict__ out) {
  // ---- pair-major XCD swizzle (R6-measured: FETCH 84.5->57MB). HW: XCD=v%8.
  const int v  = blockIdx.y * 8 + blockIdx.x;        // grid (8,72), 576 blocks
  const int p  = (v & 7) * PPX + ((v >> 3) % PPX);   // pair 0..71
  const int nb = (v >> 3) / PPX;                     // n-block 0..7
  const int n0 = nb * 256;

  // ---- map pair p -> (expert g, m-tile) via prefix sum of 128-row tile spans
  int offv[G_DIM];
#pragma unroll
  for (int i = 0; i < G_DIM; ++i) offv[i] = offs[i];

  int g = -1, tile = 0, lo = 0, hi = 0, pre = 0;
#pragma unroll
  for (int gi = 0; gi < G_DIM; ++gi) {
    const int l = gi ? offv[gi - 1] : 0;
    const int h = offv[gi];
    const int t0 = l >> 7;
    const int cnt = (h > l) ? (((h + 127) >> 7) - t0) : 0;
    if (g < 0 && p < pre + cnt) { g = gi; tile = t0 + (p - pre); lo = l; hi = h; }
    pre += cnt;
  }
  if (g < 0) return;  // dead pair; uniform per block, before any barrier

  const int m0 = tile * 128;

  __shared__ __align__(16) __hip_bfloat16 As[128 * 64];  // 16 KB
  __shared__ __align__(16) __hip_bfloat16 Bs[256 * 64];  // 32 KB

  const __hip_bfloat16* wg = wb + (size_t)g * N_DIM * K_DIM;

  const int lane = threadIdx.x & 63;
  const int wid  = threadIdx.x >> 6;   // 0..7
  const int wm   = wid >> 2;           // 0..1 -> m offset 64
  const int wn   = wid & 3;            // 0..3 -> n offset 64

  // staging: chunk = 8 rows x 64 cols = 1KB; lane l -> LDS base + l*16B.
  // row&7 == srow, so the XOR swizzle permutes the GLOBAL column block
  // (rule 21: linear dest + pre-swizzled source + swizzled read).
  const int srow = lane >> 3;                  // row within chunk
  const int scol = ((lane & 7) ^ srow) * 8;    // swizzled global col (elems)

  // A: 16 chunks, 2/wave; B: 32 chunks, 4/wave.
  const __hip_bfloat16* gA[2];
  const __hip_bfloat16* gB[4];
#pragma unroll
  for (int i = 0; i < 2; ++i) {
    const int j = wid * 2 + i;                 // 0..15
    gA[i] = xb + (size_t)(m0 + j * 8 + srow) * K_DIM + scol;
  }
#pragma unroll
  for (int i = 0; i < 4; ++i) {
    const int j = wid * 4 + i;                 // 0..31
    gB[i] = wg + (size_t)(n0 + j * 8 + srow) * K_DIM + scol;
  }

  f32x4 acc[4][4] = {};

  for (int kk = 0; kk < NT; ++kk) {
    const int k0 = kk * 64;
#pragma unroll
    for (int i = 0; i < 2; ++i)
      __builtin_amdgcn_global_load_lds((gvoid*)(gA[i] + k0),
                                       (lvoid*)(As + (wid * 2 + i) * 512), 16, 0, 0);
#pragma unroll
    for (int i = 0; i < 4; ++i)
      __builtin_amdgcn_global_load_lds((gvoid*)(gB[i] + k0),
                                       (lvoid*)(Bs + (wid * 4 + i) * 512), 16, 0, 0);
    __syncthreads();

#pragma unroll
    for (int ks = 0; ks < 2; ++ks) {
      // fragment row&7 == lane&7 -> swizzled 16B-slot offset:
      const int kb  = ks * 4 + (lane >> 4);
      const int off = ((kb ^ (lane & 7)) * 8);
      short8 a[4], b[4];
#pragma unroll
      for (int mt = 0; mt < 4; ++mt)
        a[mt] = *reinterpret_cast<const short8*>(
            As + (wm * 64 + mt * 16 + (lane & 15)) * 64 + off);
#pragma unroll
      for (int nt = 0; nt < 4; ++nt)
        b[nt] = *reinterpret_cast<const short8*>(
            Bs + (wn * 64 + nt * 16 + (lane & 15)) * 64 + off);
#pragma unroll
      for (int mt = 0; mt < 4; ++mt)
#pragma unroll
        for (int nt = 0; nt < 4; ++nt)
          acc[mt][nt] = __builtin_amdgcn_mfma_f32_16x16x32_bf16(
              a[mt], b[nt], acc[mt][nt], 0, 0, 0);
    }
    __syncthreads();
  }

  // ---- epilogue: C/D layout col=lane&15, row=(lane>>4)*4+reg [m89-verified];
  // store only rows in [lo,hi) — boundary tiles written disjointly per expert.
  const int quad = lane >> 4;
#pragma unroll
  for (int mt = 0; mt < 4; ++mt) {
    const int rbase = m0 + wm * 64 + mt * 16 + quad * 4;
#pragma unroll
    for (int r = 0; r < 4; ++r) {
      const int row = rbase + r;
      if (row < lo || row >= hi) continue;
#pragma unroll
      for (int nt = 0; nt < 4; ++nt) {
        const int col = n0 + wn * 64 + nt * 16 + (lane & 15);
        out[(size_t)row * N_DIM + col] = acc[mt][nt][r];
      }
    }
  }
}

// ---------------- fp32 fallback (only if d_ws < 48 MB; correctness-only) ----
__global__ __launch_bounds__(256) void fallback_kernel(
    const float* __restrict__ x, const float* __restrict__ w,
    const int* __restrict__ offs, float* __restrict__ out) {
  __shared__ float xs[K_DIM];
  const int t = blockIdx.y;
  int g = 0;
  while (g < G_DIM - 1 && offs[g] <= t) ++g;
  for (int i = threadIdx.x; i < K_DIM; i += blockDim.x)
    xs[i] = x[(size_t)t * K_DIM + i];
  __syncthreads();
  const int n = blockIdx.x * blockDim.x + threadIdx.x;
  const float* wr = w + ((size_t)g * N_DIM + n) * K_DIM;
  float s = 0.f;
  for (int k = 0; k < K_DIM; ++k) s += xs[k] * wr[k];
  out[(size_t)t * N_DIM + n] = s;
}

extern "C" void kernel_launch(void* const* d_in, const int* in_sizes, int n_in,
                              void* d_out, int out_size, void* d_ws, size_t ws_size,
                              hipStream_t stream) {
  const float* x    = (const float*)d_in[0];
  const float* w    = (const float*)d_in[1];
  const int*   offs = (const int*)d_in[2];
  float*       out  = (float*)d_out;

  const size_t x_elems = (size_t)T_DIM * K_DIM;            // 8.39M
  const size_t w_elems = (size_t)G_DIM * N_DIM * K_DIM;    // 16.78M
  const size_t need    = (x_elems + w_elems) * sizeof(__hip_bfloat16);  // 48 MiB

  if (ws_size < need) {
    fallback_kernel<<<dim3(N_DIM / 256, T_DIM), 256, 0, stream>>>(x, w, offs, out);
    return;
  }

  __hip_bfloat16* xb = (__hip_bfloat16*)d_ws;
  __hip_bfloat16* wb = xb + x_elems;

  const int n8x   = (int)(x_elems / 8);              // 1,048,576
  const int n8tot = (int)((x_elems + w_elems) / 8);  // 3,145,728
  cvt_kernel<<<4096, 256, 0, stream>>>(x, w, (ushort8*)xb, (ushort8*)wb,
                                       n8x, n8tot);

  grouped_gemm_kernel<<<dim3(8, MAX_PAIRS), 512, 0, stream>>>(
      xb, wb, offs, out);
}